// Round 1
// baseline (475.082 us; speedup 1.0000x reference)
//
#include <hip/hip_runtime.h>

constexpr int B = 16;
constexpr int QH = 32;
constexpr int KVH = 8;
constexpr int G = 4;            // QH / KVH
constexpr int D = 128;
constexpr int NUM_PAGES = 4096;
constexpr int TPP = 16;
constexpr int MAX_PPS = 256;
constexpr int CHUNK = 256;                       // tokens per partial block
constexpr int NCHUNK = (MAX_PPS * TPP) / CHUNK;  // 16
constexpr int PPC = CHUNK / TPP;                 // 16 pages per chunk
constexpr int WSSTRIDE = D + 2;                  // m, l, acc[128]

#define NEGF (-3.0e38f)

#define RED32(p)                 \
  do {                           \
    p += __shfl_xor(p, 16);      \
    p += __shfl_xor(p, 8);       \
    p += __shfl_xor(p, 4);       \
    p += __shfl_xor(p, 2);       \
    p += __shfl_xor(p, 1);       \
  } while (0)

// Partial flash-decode attention over one 256-token chunk of one (b, kvh).
// Block = 256 threads = 4 waves. Each half-wave (32 lanes x float4) owns one
// token per iteration: 8 tokens per block-iteration, fully coalesced 512B
// K/V reads. Two-pass per chunk: (1) scores -> LDS (+max), (2) exp/sum,
// (3) weighted V accumulate. Emits m, l, acc[128] per head into ws.
__global__ __launch_bounds__(256, 4)
void pa_partial(const float* __restrict__ qg, const float* __restrict__ kp,
                const float* __restrict__ vp, const int* __restrict__ lens,
                const int* __restrict__ pmap, float* __restrict__ ws) {
  const int c = blockIdx.x;
  const int kvh = blockIdx.y;
  const int b = blockIdx.z;
  const int start = c * CHUNK;
  int ntok = lens[b] - start;
  if (ntok <= 0) return;
  if (ntok > CHUNK) ntok = CHUNK;

  __shared__ int pages[PPC];
  __shared__ float sc[CHUNK * G];   // [t][g] scores then weights (4 KB)
  __shared__ float wred[4][4];      // per-wave head max
  __shared__ float sred[4][4];      // per-wave head expsum
  __shared__ float ared[4][G * D];  // per-wave acc staging (8 KB)

  const int tid = threadIdx.x;
  const int wave = tid >> 6;
  const int lane = tid & 63;
  const int half = lane >> 5;
  const int l32 = lane & 31;

  if (tid < PPC) pages[tid] = pmap[b * MAX_PPS + (start >> 4) + tid];
#pragma unroll
  for (int i = tid; i < CHUNK * G; i += 256) sc[i] = NEGF;
  __syncthreads();

  // Each lane holds q[g][4*l32 .. 4*l32+3] for all 4 grouped query heads.
  const float4 q0 = *(const float4*)(qg + (size_t)(b * QH + kvh * G + 0) * D + 4 * l32);
  const float4 q1 = *(const float4*)(qg + (size_t)(b * QH + kvh * G + 1) * D + 4 * l32);
  const float4 q2 = *(const float4*)(qg + (size_t)(b * QH + kvh * G + 2) * D + 4 * l32);
  const float4 q3 = *(const float4*)(qg + (size_t)(b * QH + kvh * G + 3) * D + 4 * l32);

  const size_t hoff = (size_t)kvh * NUM_PAGES * TPP * D;
  const float* kbase = kp + hoff;
  const float* vbase = vp + hoff;

  float m0 = NEGF, m1 = NEGF, m2 = NEGF, m3 = NEGF;

  const int iters = (ntok + 7) >> 3;
  const int tbase = wave * 2 + half;  // chunk-local token id at j=0

  // ---- Pass 1: scores ----
  float4 kv = make_float4(0.f, 0.f, 0.f, 0.f);
  if (tbase < ntok) {
    const int pg = pages[tbase >> 4];
    kv = *(const float4*)(kbase + ((size_t)pg * TPP + (tbase & 15)) * D + 4 * l32);
  }
  for (int j = 0; j < iters; ++j) {
    const int t = j * 8 + tbase;
    const bool valid = (t < ntok);
    const float4 cur = kv;
    const int tn = t + 8;
    if (tn < ntok) {  // software prefetch next token for this half-wave
      const int pg = pages[tn >> 4];
      kv = *(const float4*)(kbase + ((size_t)pg * TPP + (tn & 15)) * D + 4 * l32);
    }
    float p0 = cur.x * q0.x + cur.y * q0.y + cur.z * q0.z + cur.w * q0.w;
    float p1 = cur.x * q1.x + cur.y * q1.y + cur.z * q1.z + cur.w * q1.w;
    float p2 = cur.x * q2.x + cur.y * q2.y + cur.z * q2.z + cur.w * q2.w;
    float p3 = cur.x * q3.x + cur.y * q3.y + cur.z * q3.z + cur.w * q3.w;
    RED32(p0);
    RED32(p1);
    RED32(p2);
    RED32(p3);
    if (valid) {
      m0 = fmaxf(m0, p0);
      m1 = fmaxf(m1, p1);
      m2 = fmaxf(m2, p2);
      m3 = fmaxf(m3, p3);
      if (l32 == 0) *(float4*)(sc + t * G) = make_float4(p0, p1, p2, p3);
    }
  }
  m0 = fmaxf(m0, __shfl_xor(m0, 32));
  m1 = fmaxf(m1, __shfl_xor(m1, 32));
  m2 = fmaxf(m2, __shfl_xor(m2, 32));
  m3 = fmaxf(m3, __shfl_xor(m3, 32));
  if (lane == 0) {
    wred[wave][0] = m0;
    wred[wave][1] = m1;
    wred[wave][2] = m2;
    wred[wave][3] = m3;
  }
  __syncthreads();

  // ---- block max per head, then exp + sum ----
  const float M0 = fmaxf(fmaxf(wred[0][0], wred[1][0]), fmaxf(wred[2][0], wred[3][0]));
  const float M1 = fmaxf(fmaxf(wred[0][1], wred[1][1]), fmaxf(wred[2][1], wred[3][1]));
  const float M2 = fmaxf(fmaxf(wred[0][2], wred[1][2]), fmaxf(wred[2][2], wred[3][2]));
  const float M3 = fmaxf(fmaxf(wred[0][3], wred[1][3]), fmaxf(wred[2][3], wred[3][3]));
  // this thread's strided entries all have head g = tid & 3 (static select)
  const float Ma = (tid & 1) ? M1 : M0;
  const float Mb = (tid & 1) ? M3 : M2;
  const float Mg = (tid & 2) ? Mb : Ma;

  float lsum = 0.f;
#pragma unroll
  for (int i = tid; i < CHUNK * G; i += 256) {
    const float e = __expf(sc[i] - Mg);  // masked entries (-3e38) -> 0
    sc[i] = e;
    lsum += e;
  }
  lsum += __shfl_xor(lsum, 4);
  lsum += __shfl_xor(lsum, 8);
  lsum += __shfl_xor(lsum, 16);
  lsum += __shfl_xor(lsum, 32);
  if (lane < 4) sred[wave][lane] = lsum;
  __syncthreads();  // weights in sc visible to all waves

  // ---- Pass 2: weighted V accumulate ----
  float4 a0 = make_float4(0.f, 0.f, 0.f, 0.f);
  float4 a1 = a0, a2 = a0, a3 = a0;
  float4 vv = make_float4(0.f, 0.f, 0.f, 0.f);
  if (tbase < ntok) {
    const int pg = pages[tbase >> 4];
    vv = *(const float4*)(vbase + ((size_t)pg * TPP + (tbase & 15)) * D + 4 * l32);
  }
  for (int j = 0; j < iters; ++j) {
    const int t = j * 8 + tbase;
    const bool valid = (t < ntok);
    const float4 cur = vv;
    const int tn = t + 8;
    if (tn < ntok) {
      const int pg = pages[tn >> 4];
      vv = *(const float4*)(vbase + ((size_t)pg * TPP + (tn & 15)) * D + 4 * l32);
    }
    if (valid) {
      const float4 wv = *(const float4*)(sc + t * G);  // broadcast within half
      a0.x += wv.x * cur.x; a0.y += wv.x * cur.y; a0.z += wv.x * cur.z; a0.w += wv.x * cur.w;
      a1.x += wv.y * cur.x; a1.y += wv.y * cur.y; a1.z += wv.y * cur.z; a1.w += wv.y * cur.w;
      a2.x += wv.z * cur.x; a2.y += wv.z * cur.y; a2.z += wv.z * cur.z; a2.w += wv.z * cur.w;
      a3.x += wv.w * cur.x; a3.y += wv.w * cur.y; a3.z += wv.w * cur.z; a3.w += wv.w * cur.w;
    }
  }
  // combine the two halves (same dims, different token subsets)
  a0.x += __shfl_xor(a0.x, 32); a0.y += __shfl_xor(a0.y, 32);
  a0.z += __shfl_xor(a0.z, 32); a0.w += __shfl_xor(a0.w, 32);
  a1.x += __shfl_xor(a1.x, 32); a1.y += __shfl_xor(a1.y, 32);
  a1.z += __shfl_xor(a1.z, 32); a1.w += __shfl_xor(a1.w, 32);
  a2.x += __shfl_xor(a2.x, 32); a2.y += __shfl_xor(a2.y, 32);
  a2.z += __shfl_xor(a2.z, 32); a2.w += __shfl_xor(a2.w, 32);
  a3.x += __shfl_xor(a3.x, 32); a3.y += __shfl_xor(a3.y, 32);
  a3.z += __shfl_xor(a3.z, 32); a3.w += __shfl_xor(a3.w, 32);
  if (half == 0) {
    *(float4*)(ared[wave] + 0 * D + 4 * l32) = a0;
    *(float4*)(ared[wave] + 1 * D + 4 * l32) = a1;
    *(float4*)(ared[wave] + 2 * D + 4 * l32) = a2;
    *(float4*)(ared[wave] + 3 * D + 4 * l32) = a3;
  }
  __syncthreads();

  // ---- write partials: [b][kvh][c][g]{m, l, acc[128]} ----
  const size_t wsbase = ((size_t)((b * KVH + kvh) * NCHUNK + c) * G) * WSSTRIDE;
#pragma unroll
  for (int r = 0; r < 2; ++r) {
    const int idx = tid + r * 256;  // 0..511
    const int g = idx >> 7;
    const int d = idx & 127;
    const float v =
        ared[0][g * D + d] + ared[1][g * D + d] + ared[2][g * D + d] + ared[3][g * D + d];
    ws[wsbase + (size_t)g * WSSTRIDE + 2 + d] = v;
  }
  if (tid < 4) {  // tid == g here, and Mg == M[tid]
    ws[wsbase + (size_t)tid * WSSTRIDE + 0] = Mg;
    ws[wsbase + (size_t)tid * WSSTRIDE + 1] =
        sred[0][tid] + sred[1][tid] + sred[2][tid] + sred[3][tid];
  }
}

// Combine partial chunks: one block per (b, kvh, g), thread = dim d.
__global__ __launch_bounds__(128)
void pa_reduce(const float* __restrict__ ws, const int* __restrict__ lens,
               float* __restrict__ out) {
  const int g = blockIdx.x;
  const int kvh = blockIdx.y;
  const int b = blockIdx.z;
  const int d = threadIdx.x;
  const int nc = (lens[b] + CHUNK - 1) / CHUNK;  // >= 1
  float M = NEGF, L = 0.f, acc = 0.f;
  for (int c = 0; c < nc; ++c) {
    const float* p =
        ws + ((size_t)((b * KVH + kvh) * NCHUNK + c) * G + g) * WSSTRIDE;
    const float mc = p[0];
    const float lc = p[1];
    const float ac = p[2 + d];
    const float Mn = fmaxf(M, mc);
    const float so = __expf(M - Mn);
    const float se = __expf(mc - Mn);
    L = L * so + lc * se;
    acc = acc * so + ac * se;
    M = Mn;
  }
  out[(size_t)(b * QH + kvh * G + g) * D + d] = acc / L;
}

extern "C" void kernel_launch(void* const* d_in, const int* in_sizes, int n_in,
                              void* d_out, int out_size, void* d_ws, size_t ws_size,
                              hipStream_t stream) {
  (void)in_sizes; (void)n_in; (void)out_size; (void)ws_size;
  const float* q = (const float*)d_in[0];
  const float* kp = (const float*)d_in[1];
  const float* vp = (const float*)d_in[2];
  const int* lens = (const int*)d_in[3];
  const int* pmap = (const int*)d_in[4];
  float* out = (float*)d_out;
  float* ws = (float*)d_ws;  // needs 16*8*16*4*130*4 B ~= 4.26 MB

  dim3 g1(NCHUNK, KVH, B);   // (16, 8, 16) = 2048 blocks
  pa_partial<<<g1, 256, 0, stream>>>(q, kp, vp, lens, pmap, ws);
  dim3 g2(G, KVH, B);        // (4, 8, 16) = 512 blocks
  pa_reduce<<<g2, 128, 0, stream>>>(ws, lens, out);
}

// Round 2
// 471.818 us; speedup vs baseline: 1.0069x; 1.0069x over previous
//
#include <hip/hip_runtime.h>

constexpr int B = 16;
constexpr int QH = 32;
constexpr int KVH = 8;
constexpr int G = 4;            // QH / KVH
constexpr int D = 128;
constexpr int NUM_PAGES = 4096;
constexpr int TPP = 16;
constexpr int MAX_PPS = 256;
constexpr int CHUNK = 256;                       // tokens per partial block
constexpr int NCHUNK = (MAX_PPS * TPP) / CHUNK;  // 16
constexpr int PPC = CHUNK / TPP;                 // 16 pages per chunk
constexpr int WSSTRIDE = D + 2;                  // m, l, acc[128]

#define NEGF (-3.0e38f)
#define DEFER_T 8.0f

#define RED32(p)                 \
  do {                           \
    p += __shfl_xor(p, 16);      \
    p += __shfl_xor(p, 8);       \
    p += __shfl_xor(p, 4);       \
    p += __shfl_xor(p, 2);       \
    p += __shfl_xor(p, 1);       \
  } while (0)

// Fused single-pass flash-decode partial over one 256-token chunk of (b,kvh).
// Block = 256 threads = 4 waves; each half-wave (32 lanes x float4) owns one
// token per iteration (8 tokens/block-iter). K and V for a token are loaded
// together, with depth-2 token prefetch (4 x 512B in flight per wave).
// Online softmax with deferred rescale (THR=8): exp(p - mref) with mref only
// advanced when p > mref + 8, so the common path is 4 exp + 32 FMA per iter.
__global__ __launch_bounds__(256, 4)
void pa_partial(const float* __restrict__ qg, const float* __restrict__ kp,
                const float* __restrict__ vp, const int* __restrict__ lens,
                const int* __restrict__ pmap, float* __restrict__ ws) {
  // Diagonal swizzle: CU-resident blocks (stride ~256 apart) span different
  // (b, chunk) pairs -> per-CU work balanced across sequence lengths.
  const int f = blockIdx.x;      // 0..2047
  const int hi = f >> 7;         // 0..15
  const int lo = f & 127;
  const int b = ((lo & 15) + hi) & 15;
  const int kvh = lo >> 4;
  const int c = hi;

  const int start = c * CHUNK;
  int ntok = lens[b] - start;
  if (ntok <= 0) return;
  if (ntok > CHUNK) ntok = CHUNK;

  __shared__ int pages[PPC];
  __shared__ float wred[4][4];      // per-wave head max (mref)
  __shared__ float sred[4][4];      // per-wave head expsum (rescaled)
  __shared__ float ared[4][G * D];  // per-wave acc staging (8 KB)

  const int tid = threadIdx.x;
  const int wave = tid >> 6;
  const int lane = tid & 63;
  const int half = lane >> 5;
  const int l32 = lane & 31;

  if (tid < PPC) pages[tid] = pmap[b * MAX_PPS + (start >> 4) + tid];
  __syncthreads();

  // Each lane holds q[g][4*l32 .. 4*l32+3] for all 4 grouped query heads.
  const float4 q0 = *(const float4*)(qg + (size_t)(b * QH + kvh * G + 0) * D + 4 * l32);
  const float4 q1 = *(const float4*)(qg + (size_t)(b * QH + kvh * G + 1) * D + 4 * l32);
  const float4 q2 = *(const float4*)(qg + (size_t)(b * QH + kvh * G + 2) * D + 4 * l32);
  const float4 q3 = *(const float4*)(qg + (size_t)(b * QH + kvh * G + 3) * D + 4 * l32);

  const size_t hoff = (size_t)kvh * NUM_PAGES * TPP * D;
  const float* kbase = kp + hoff;
  const float* vbase = vp + hoff;

  const int iters = (ntok + 7) >> 3;
  const int tbase = wave * 2 + half;  // chunk-local token at j=0

  // Clamped token -> address (tail prefetches re-read the last page: harmless,
  // always valid memory since pmap is fully initialized).
  auto kvoff = [&](int t) -> size_t {
    const int pi = min(t >> 4, PPC - 1);
    return ((size_t)pages[pi] * TPP + (t & 15)) * D + 4 * l32;
  };

  float m0 = NEGF, m1 = NEGF, m2 = NEGF, m3 = NEGF;
  float l0 = 0.f, l1 = 0.f, l2 = 0.f, l3 = 0.f;
  float4 a0 = make_float4(0.f, 0.f, 0.f, 0.f);
  float4 a1 = a0, a2 = a0, a3 = a0;

  // Depth-2 pipeline: slots A (iter j) and B (iter j+1).
  size_t o = kvoff(tbase);
  float4 kA = *(const float4*)(kbase + o);
  float4 vA = *(const float4*)(vbase + o);
  o = kvoff(tbase + 8);
  float4 kB = *(const float4*)(kbase + o);
  float4 vB = *(const float4*)(vbase + o);

  for (int j = 0; j < iters; ++j) {
    const int t = tbase + 8 * j;
    const bool valid = (t < ntok);
    const float4 ck = kA, cv = vA;
    kA = kB; vA = vB;
    o = kvoff(tbase + 8 * (j + 2));
    kB = *(const float4*)(kbase + o);
    vB = *(const float4*)(vbase + o);

    float p0 = ck.x * q0.x + ck.y * q0.y + ck.z * q0.z + ck.w * q0.w;
    float p1 = ck.x * q1.x + ck.y * q1.y + ck.z * q1.z + ck.w * q1.w;
    float p2 = ck.x * q2.x + ck.y * q2.y + ck.z * q2.z + ck.w * q2.w;
    float p3 = ck.x * q3.x + ck.y * q3.y + ck.z * q3.z + ck.w * q3.w;
    RED32(p0);
    RED32(p1);
    RED32(p2);
    RED32(p3);

    if (valid) {  // half-uniform branch
      const float dmax = fmaxf(fmaxf(p0 - m0, p1 - m1), fmaxf(p2 - m2, p3 - m3));
      if (dmax > DEFER_T) {  // rare: advance reference max, rescale state
        const float n0 = fmaxf(m0, p0), n1 = fmaxf(m1, p1);
        const float n2 = fmaxf(m2, p2), n3 = fmaxf(m3, p3);
        const float s0 = __expf(m0 - n0), s1 = __expf(m1 - n1);
        const float s2 = __expf(m2 - n2), s3 = __expf(m3 - n3);
        l0 *= s0; l1 *= s1; l2 *= s2; l3 *= s3;
        a0.x *= s0; a0.y *= s0; a0.z *= s0; a0.w *= s0;
        a1.x *= s1; a1.y *= s1; a1.z *= s1; a1.w *= s1;
        a2.x *= s2; a2.y *= s2; a2.z *= s2; a2.w *= s2;
        a3.x *= s3; a3.y *= s3; a3.z *= s3; a3.w *= s3;
        m0 = n0; m1 = n1; m2 = n2; m3 = n3;
      }
      const float e0 = __expf(p0 - m0);
      const float e1 = __expf(p1 - m1);
      const float e2 = __expf(p2 - m2);
      const float e3 = __expf(p3 - m3);
      l0 += e0; l1 += e1; l2 += e2; l3 += e3;
      a0.x += e0 * cv.x; a0.y += e0 * cv.y; a0.z += e0 * cv.z; a0.w += e0 * cv.w;
      a1.x += e1 * cv.x; a1.y += e1 * cv.y; a1.z += e1 * cv.z; a1.w += e1 * cv.w;
      a2.x += e2 * cv.x; a2.y += e2 * cv.y; a2.z += e2 * cv.z; a2.w += e2 * cv.w;
      a3.x += e3 * cv.x; a3.y += e3 * cv.y; a3.z += e3 * cv.z; a3.w += e3 * cv.w;
    }
  }

  // ---- merge the two halves of each wave (different tokens, same dims) ----
#define HMERGE(m, l, a)                                                   \
  do {                                                                    \
    const float pm = __shfl_xor(m, 32), pl = __shfl_xor(l, 32);           \
    float4 pa;                                                            \
    pa.x = __shfl_xor(a.x, 32); pa.y = __shfl_xor(a.y, 32);               \
    pa.z = __shfl_xor(a.z, 32); pa.w = __shfl_xor(a.w, 32);               \
    const float M = fmaxf(m, pm);                                         \
    const float sa = __expf(m - M), sb = __expf(pm - M);                  \
    l = l * sa + pl * sb;                                                 \
    a.x = a.x * sa + pa.x * sb; a.y = a.y * sa + pa.y * sb;               \
    a.z = a.z * sa + pa.z * sb; a.w = a.w * sa + pa.w * sb;               \
    m = M;                                                                \
  } while (0)
  HMERGE(m0, l0, a0);
  HMERGE(m1, l1, a1);
  HMERGE(m2, l2, a2);
  HMERGE(m3, l3, a3);
#undef HMERGE

  // ---- merge the 4 waves via LDS with per-wave rescale ----
  if (lane == 0) {
    wred[wave][0] = m0; wred[wave][1] = m1; wred[wave][2] = m2; wred[wave][3] = m3;
  }
  __syncthreads();
  const float M0 = fmaxf(fmaxf(wred[0][0], wred[1][0]), fmaxf(wred[2][0], wred[3][0]));
  const float M1 = fmaxf(fmaxf(wred[0][1], wred[1][1]), fmaxf(wred[2][1], wred[3][1]));
  const float M2 = fmaxf(fmaxf(wred[0][2], wred[1][2]), fmaxf(wred[2][2], wred[3][2]));
  const float M3 = fmaxf(fmaxf(wred[0][3], wred[1][3]), fmaxf(wred[2][3], wred[3][3]));
  const float s0 = __expf(m0 - M0), s1 = __expf(m1 - M1);
  const float s2 = __expf(m2 - M2), s3 = __expf(m3 - M3);
  if (half == 0) {
    *(float4*)(ared[wave] + 0 * D + 4 * l32) =
        make_float4(a0.x * s0, a0.y * s0, a0.z * s0, a0.w * s0);
    *(float4*)(ared[wave] + 1 * D + 4 * l32) =
        make_float4(a1.x * s1, a1.y * s1, a1.z * s1, a1.w * s1);
    *(float4*)(ared[wave] + 2 * D + 4 * l32) =
        make_float4(a2.x * s2, a2.y * s2, a2.z * s2, a2.w * s2);
    *(float4*)(ared[wave] + 3 * D + 4 * l32) =
        make_float4(a3.x * s3, a3.y * s3, a3.z * s3, a3.w * s3);
  }
  if (lane == 0) {
    sred[wave][0] = l0 * s0; sred[wave][1] = l1 * s1;
    sred[wave][2] = l2 * s2; sred[wave][3] = l3 * s3;
  }
  __syncthreads();

  // ---- write partials: [b][kvh][c][g]{m, l, acc[128]} ----
  const size_t wsbase = ((size_t)((b * KVH + kvh) * NCHUNK + c) * G) * WSSTRIDE;
#pragma unroll
  for (int r = 0; r < 2; ++r) {
    const int idx = tid + r * 256;  // 0..511
    const int g = idx >> 7;
    const int d = idx & 127;
    const float v =
        ared[0][g * D + d] + ared[1][g * D + d] + ared[2][g * D + d] + ared[3][g * D + d];
    ws[wsbase + (size_t)g * WSSTRIDE + 2 + d] = v;
  }
  if (tid < 4) {  // tid == g; block-max for head g (uniform values)
    const float Ma = (tid & 1) ? M1 : M0;
    const float Mb = (tid & 1) ? M3 : M2;
    const float Mg = (tid & 2) ? Mb : Ma;
    ws[wsbase + (size_t)tid * WSSTRIDE + 0] = Mg;
    ws[wsbase + (size_t)tid * WSSTRIDE + 1] =
        sred[0][tid] + sred[1][tid] + sred[2][tid] + sred[3][tid];
  }
}

// Combine partial chunks: one block per (b, kvh, g), thread = dim d.
__global__ __launch_bounds__(128)
void pa_reduce(const float* __restrict__ ws, const int* __restrict__ lens,
               float* __restrict__ out) {
  const int g = blockIdx.x;
  const int kvh = blockIdx.y;
  const int b = blockIdx.z;
  const int d = threadIdx.x;
  const int nc = (lens[b] + CHUNK - 1) / CHUNK;  // >= 1
  float M = NEGF, L = 0.f, acc = 0.f;
  for (int c = 0; c < nc; ++c) {
    const float* p =
        ws + ((size_t)((b * KVH + kvh) * NCHUNK + c) * G + g) * WSSTRIDE;
    const float mc = p[0];
    const float lc = p[1];
    const float ac = p[2 + d];
    const float Mn = fmaxf(M, mc);
    const float so = __expf(M - Mn);
    const float se = __expf(mc - Mn);
    L = L * so + lc * se;
    acc = acc * so + ac * se;
    M = Mn;
  }
  out[(size_t)(b * QH + kvh * G + g) * D + d] = acc / L;
}

extern "C" void kernel_launch(void* const* d_in, const int* in_sizes, int n_in,
                              void* d_out, int out_size, void* d_ws, size_t ws_size,
                              hipStream_t stream) {
  (void)in_sizes; (void)n_in; (void)out_size; (void)ws_size;
  const float* q = (const float*)d_in[0];
  const float* kp = (const float*)d_in[1];
  const float* vp = (const float*)d_in[2];
  const int* lens = (const int*)d_in[3];
  const int* pmap = (const int*)d_in[4];
  float* out = (float*)d_out;
  float* ws = (float*)d_ws;  // needs 16*8*16*4*130*4 B ~= 4.26 MB

  pa_partial<<<NCHUNK * KVH * B, 256, 0, stream>>>(q, kp, vp, lens, pmap, ws);
  dim3 g2(G, KVH, B);  // (4, 8, 16) = 512 blocks
  pa_reduce<<<g2, 128, 0, stream>>>(ws, lens, out);
}